// Round 5
// baseline (487.736 us; speedup 1.0000x reference)
//
#include <hip/hip_runtime.h>
#include <hip/hip_bf16.h>

#define ALPHA 0.2f

typedef __attribute__((ext_vector_type(8)))  __bf16 bf16x8;
typedef int          i32x4 __attribute__((ext_vector_type(4)));
typedef float        f32x4 __attribute__((ext_vector_type(4)));
typedef unsigned int u32x4 __attribute__((ext_vector_type(4)));

static __device__ __forceinline__ unsigned short bf16bits(float v) {
    __bf16 b = (__bf16)v;
    unsigned short u;
    __builtin_memcpy(&u, &b, 2);
    return u;
}

// ---------- Kernel 1: h = x*W ; f1 = h@a1 ; f2 = h@a2 ; hB = 16x16x32 B-fragment-packed h ----------
// hB layout: frag id = ks32*8 + ft16  (ks32 = j/32, ft16 = f/16), 512 bf16 per frag:
//   element(lane s, e) = h[j = ks32*32 + (s>>4)*8 + e][f = ft16*16 + (s&15)] at frag*512 + s*8 + e
__global__ __launch_bounds__(256) void gat_prep(
    const float* __restrict__ x, const float* __restrict__ W, const float* __restrict__ a,
    float* __restrict__ f1, float* __restrict__ f2, unsigned short* __restrict__ hB,
    float* __restrict__ ws_acc)
{
    __shared__ unsigned short lh[32][136];   // [j-local][f]
    int t = threadIdx.x;
    int i0 = blockIdx.x * 32;
    if (blockIdx.x == 0 && t < 128) ws_acc[t] = 0.0f;

    int row = t >> 3, q = t & 7;             // 8 threads per row, 16 f each
    int i = i0 + row;
    const float4* xp  = (const float4*)(x + (size_t)i * 128 + q * 16);
    const float4* wp  = (const float4*)(W + (size_t)i * 128 + q * 16);
    const float4* a1p = (const float4*)(a + q * 16);
    const float4* a2p = (const float4*)(a + 128 + q * 16);
    float p1 = 0.f, p2 = 0.f;
    #pragma unroll
    for (int jj = 0; jj < 4; ++jj) {
        float4 xv = xp[jj], wv = wp[jj], a1v = a1p[jj], a2v = a2p[jj];
        float h0 = xv.x * wv.x, h1 = xv.y * wv.y, h2 = xv.z * wv.z, h3 = xv.w * wv.w;
        p1 += h0 * a1v.x + h1 * a1v.y + h2 * a1v.z + h3 * a1v.w;
        p2 += h0 * a2v.x + h1 * a2v.y + h2 * a2v.z + h3 * a2v.w;
        int fb = q * 16 + jj * 4;
        lh[row][fb + 0] = bf16bits(h0);
        lh[row][fb + 1] = bf16bits(h1);
        lh[row][fb + 2] = bf16bits(h2);
        lh[row][fb + 3] = bf16bits(h3);
    }
    p1 += __shfl_xor(p1, 1); p1 += __shfl_xor(p1, 2); p1 += __shfl_xor(p1, 4);
    p2 += __shfl_xor(p2, 1); p2 += __shfl_xor(p2, 2); p2 += __shfl_xor(p2, 4);
    if (q == 0) { f1[i] = p1; f2[i] = p2; }
    __syncthreads();

    // fragment-pack: this block is exactly ks32 = blockIdx.x (32 j rows)
    int ftl = t >> 5, s0 = t & 31;
    size_t fragbase = ((size_t)blockIdx.x * 8 + ftl) * 512;
    #pragma unroll
    for (int hw = 0; hw < 2; ++hw) {
        int s = s0 + hw * 32;
        int jl = (s >> 4) * 8;
        int f = ftl * 16 + (s & 15);
        unsigned int p[4];
        #pragma unroll
        for (int k = 0; k < 4; ++k) {
            unsigned int lo = lh[jl + 2 * k][f];
            unsigned int hi = lh[jl + 2 * k + 1][f];
            p[k] = lo | (hi << 16);
        }
        u32x4 v = {p[0], p[1], p[2], p[3]};
        *(u32x4*)(hB + fragbase + s * 8) = v;
    }
}

// ---------- Kernel 2: wave-autonomous fused attention + adj@W2 row sums ----------
// 512 blocks x 256 threads (4 waves). Block owns 16 rows; wave w owns j in [w*2048,(w+1)*2048).
// NO barriers in the K-loop: each wave stages wg in its PRIVATE LDS region (same-wave
// lgkmcnt ordering only), reads it back in MFMA A-layout, MFMAs against L2-resident hB.
// One __syncthreads at the end for the 4-way j-split reduction.
__global__ __launch_bounds__(256, 2) void gat_main(
    const int* __restrict__ adj, const float* __restrict__ x,
    const float* __restrict__ W2, const float* __restrict__ f1g,
    const float* __restrict__ f2g, const unsigned short* __restrict__ hB,
    float* __restrict__ hp, float* __restrict__ ws_acc)
{
    __shared__ unsigned short tile[4][16][264];   // 33 KB, per-wave private 16x256 wg tiles
    __shared__ float den_s[4][16], rs_s[4][16];

    int tid = threadIdx.x;
    int w = tid >> 6, l = tid & 63;
    int i0 = blockIdx.x * 16;

    float f1r[16];
    #pragma unroll
    for (int r = 0; r < 16; ++r) f1r[r] = f1g[i0 + r];

    float den[16], rs[16];
    #pragma unroll
    for (int r = 0; r < 16; ++r) { den[r] = 0.f; rs[r] = 0.f; }
    f32x4 acc[8] = {};

    const int jbase0 = w * 2048;
    const int* arow = adj + (size_t)i0 * 8192 + jbase0 + l * 4;
    const float* f2p = f2g + jbase0 + l * 4;
    const float* w2p = W2 + jbase0 + l * 4;

    i32x4 adjreg[16];
    f32x4 f2v, w2v;
    auto issue = [&](int c) {
        int jo = c * 256;
        f2v = *(const f32x4*)(f2p + jo);
        w2v = *(const f32x4*)(w2p + jo);
        #pragma unroll
        for (int r = 0; r < 16; ++r)
            adjreg[r] = __builtin_nontemporal_load(
                (const i32x4*)(arow + (size_t)r * 8192 + jo));
    };
    issue(0);

    const unsigned short* hBw = hB + (size_t)w * 262144 + l * 8;  // wave's ks-quarter
    const unsigned short* ap  = &tile[w][l & 15][(l >> 4) * 8];   // A-frag base

    for (int c = 0; c < 8; ++c) {
        // ---- consume chunk c: wg -> private LDS tile, den/rs lane-local ----
        #pragma unroll
        for (int r = 0; r < 16; ++r) {
            i32x4 ad = adjreg[r];
            float g[4];
            float dsum = 0.f, rsum = 0.f;
            #pragma unroll
            for (int e = 0; e < 4; ++e) {
                float tt = f1r[r] + f2v[e];
                float lr = fmaxf(tt, ALPHA * tt);     // leakyrelu
                float ex = __expf(lr);
                float gg = (ad[e] != 0) ? ex : 0.0f;
                g[e] = gg;
                dsum += gg;
                rsum += (ad[e] != 0) ? w2v[e] : 0.0f;
            }
            den[r] += dsum;
            rs[r] += rsum;
            unsigned int p0 = bf16bits(g[0]) | ((unsigned int)bf16bits(g[1]) << 16);
            unsigned int p1 = bf16bits(g[2]) | ((unsigned int)bf16bits(g[3]) << 16);
            *(uint2*)&tile[w][r][l * 4] = make_uint2(p0, p1);
        }
        // ---- prefetch chunk c+1 (stays in flight through the MFMA phase; no barrier) ----
        if (c < 7) issue(c + 1);
        // ---- MFMA chunk c: A from private LDS, B from L2-resident hB ----
        const unsigned short* bp = hBw + (size_t)c * 32768;
        #pragma unroll
        for (int ksl = 0; ksl < 8; ++ksl) {
            bf16x8 af = *(const bf16x8*)(ap + ksl * 32);
            const unsigned short* bk = bp + (size_t)ksl * 4096;
            #pragma unroll
            for (int ft = 0; ft < 8; ++ft) {
                bf16x8 bf = *(const bf16x8*)(bk + ft * 512);
                acc[ft] = __builtin_amdgcn_mfma_f32_16x16x32_bf16(af, bf, acc[ft], 0, 0, 0);
            }
        }
    }

    // ---- lane reduction of den/rs, stash per-wave sums ----
    #pragma unroll
    for (int r = 0; r < 16; ++r) {
        float d = den[r], rr = rs[r];
        #pragma unroll
        for (int off = 1; off < 64; off <<= 1) {
            d += __shfl_xor(d, off);
            rr += __shfl_xor(rr, off);
        }
        if (l == 0) { den_s[w][r] = d; rs_s[w][r] = rr; }
    }

    // ---- 4-way j-split acc reduction (single barrier; reuse tile as float buffer) ----
    float* av = (float*)acc;
    if (w != 0) {
        float* dst = (float*)&tile[0][0][0] + (size_t)(w - 1) * 2048;
        #pragma unroll
        for (int j = 0; j < 32; ++j) dst[j * 64 + l] = av[j];
    }
    __syncthreads();

    if (w == 0) {
        #pragma unroll
        for (int ww = 0; ww < 3; ++ww) {
            const float* srcp = (const float*)&tile[0][0][0] + (size_t)ww * 2048;
            #pragma unroll
            for (int j = 0; j < 32; ++j) av[j] += srcp[j * 64 + l];
        }
        int q = l >> 4, col = l & 15;
        float inv[4];
        #pragma unroll
        for (int reg = 0; reg < 4; ++reg) {
            int row = q * 4 + reg;
            float dsum = den_s[0][row] + den_s[1][row] + den_s[2][row] + den_s[3][row];
            inv[reg] = (dsum != 0.f) ? 1.0f / dsum : 0.f;
        }
        #pragma unroll
        for (int ft = 0; ft < 8; ++ft) {
            #pragma unroll
            for (int reg = 0; reg < 4; ++reg) {
                int row = q * 4 + reg;
                __builtin_nontemporal_store(acc[ft][reg] * inv[reg],
                    hp + (size_t)(i0 + row) * 128 + ft * 16 + col);
            }
        }
    } else if (w == 1) {
        // out-path partial: sum_i rs[i] * x[i][:] over this block's 16 rows
        float px = 0.f, py = 0.f;
        #pragma unroll
        for (int r = 0; r < 16; ++r) {
            float rm = rs_s[0][r] + rs_s[1][r] + rs_s[2][r] + rs_s[3][r];
            const float* xr = x + (size_t)(i0 + r) * 128;
            px += rm * xr[l];
            py += rm * xr[l + 64];
        }
        atomicAdd(ws_acc + l, px);
        atomicAdd(ws_acc + l + 64, py);
    }
}

// ---------- Kernel 3: elu epilogue ----------
__global__ __launch_bounds__(128) void gat_finish(const float* __restrict__ ws_acc,
                                                  float* __restrict__ out)
{
    int t = threadIdx.x;
    float v = ws_acc[t];
    out[t] = (v > 0.f) ? v : (__expf(v) - 1.0f);
}

extern "C" void kernel_launch(void* const* d_in, const int* in_sizes, int n_in,
                              void* d_out, int out_size, void* d_ws, size_t ws_size,
                              hipStream_t stream) {
    const float* x   = (const float*)d_in[0];
    const int*   adj = (const int*)d_in[1];
    const float* W   = (const float*)d_in[2];
    const float* a   = (const float*)d_in[3];
    const float* W2  = (const float*)d_in[4];
    float* out = (float*)d_out;              // [0:128] elu out, [128:] h_prime [8192][128]

    float* wsf    = (float*)d_ws;
    float* ws_acc = wsf;                     // 128 floats
    float* f1     = wsf + 128;               // 8192 floats
    float* f2     = wsf + 128 + 8192;        // 8192 floats
    unsigned short* hB = (unsigned short*)(wsf + 128 + 2 * 8192);  // bf16, 2 MB fragment-packed

    gat_prep<<<256, 256, 0, stream>>>(x, W, a, f1, f2, hB, ws_acc);
    gat_main<<<512, 256, 0, stream>>>(adj, x, W2, f1, f2, hB, out + 128, ws_acc);
    gat_finish<<<1, 128, 0, stream>>>(ws_acc, out);
}

// Round 8
// 388.396 us; speedup vs baseline: 1.2558x; 1.2558x over previous
//
#include <hip/hip_runtime.h>
#include <hip/hip_bf16.h>

#define ALPHA 0.2f

typedef __attribute__((ext_vector_type(8)))  __bf16 bf16x8;
typedef int          i32x4 __attribute__((ext_vector_type(4)));
typedef float        f32x4 __attribute__((ext_vector_type(4)));
typedef unsigned int u32x4 __attribute__((ext_vector_type(4)));

static __device__ __forceinline__ unsigned short bf16bits(float v) {
    __bf16 b = (__bf16)v;
    unsigned short u;
    __builtin_memcpy(&u, &b, 2);
    return u;
}

// ---------- Kernel 1: h = x*W ; f1 = h@a1 ; f2 = h@a2 ; hB = 16x16x32 B-fragment-packed h ----------
// hB layout: frag id = ks32*8 + ft16  (ks32 = j/32, ft16 = f/16), 512 bf16 per frag:
//   element(lane s, e) = h[j = ks32*32 + (s>>4)*8 + e][f = ft16*16 + (s&15)] at frag*512 + s*8 + e
__global__ __launch_bounds__(256) void gat_prep(
    const float* __restrict__ x, const float* __restrict__ W, const float* __restrict__ a,
    float* __restrict__ f1, float* __restrict__ f2, unsigned short* __restrict__ hB,
    float* __restrict__ ws_acc)
{
    __shared__ unsigned short lh[32][136];   // [j-local][f]
    int t = threadIdx.x;
    int i0 = blockIdx.x * 32;
    if (blockIdx.x == 0 && t < 128) ws_acc[t] = 0.0f;

    int row = t >> 3, q = t & 7;             // 8 threads per row, 16 f each
    int i = i0 + row;
    const float4* xp  = (const float4*)(x + (size_t)i * 128 + q * 16);
    const float4* wp  = (const float4*)(W + (size_t)i * 128 + q * 16);
    const float4* a1p = (const float4*)(a + q * 16);
    const float4* a2p = (const float4*)(a + 128 + q * 16);
    float p1 = 0.f, p2 = 0.f;
    #pragma unroll
    for (int jj = 0; jj < 4; ++jj) {
        float4 xv = xp[jj], wv = wp[jj], a1v = a1p[jj], a2v = a2p[jj];
        float h0 = xv.x * wv.x, h1 = xv.y * wv.y, h2 = xv.z * wv.z, h3 = xv.w * wv.w;
        p1 += h0 * a1v.x + h1 * a1v.y + h2 * a1v.z + h3 * a1v.w;
        p2 += h0 * a2v.x + h1 * a2v.y + h2 * a2v.z + h3 * a2v.w;
        int fb = q * 16 + jj * 4;
        lh[row][fb + 0] = bf16bits(h0);
        lh[row][fb + 1] = bf16bits(h1);
        lh[row][fb + 2] = bf16bits(h2);
        lh[row][fb + 3] = bf16bits(h3);
    }
    p1 += __shfl_xor(p1, 1); p1 += __shfl_xor(p1, 2); p1 += __shfl_xor(p1, 4);
    p2 += __shfl_xor(p2, 1); p2 += __shfl_xor(p2, 2); p2 += __shfl_xor(p2, 4);
    if (q == 0) { f1[i] = p1; f2[i] = p2; }
    __syncthreads();

    // fragment-pack: this block is exactly ks32 = blockIdx.x (32 j rows)
    int ftl = t >> 5, s0 = t & 31;
    size_t fragbase = ((size_t)blockIdx.x * 8 + ftl) * 512;
    #pragma unroll
    for (int hw = 0; hw < 2; ++hw) {
        int s = s0 + hw * 32;
        int jl = (s >> 4) * 8;
        int f = ftl * 16 + (s & 15);
        unsigned int p[4];
        #pragma unroll
        for (int k = 0; k < 4; ++k) {
            unsigned int lo = lh[jl + 2 * k][f];
            unsigned int hi = lh[jl + 2 * k + 1][f];
            p[k] = lo | (hi << 16);
        }
        u32x4 v = {p[0], p[1], p[2], p[3]};
        *(u32x4*)(hB + fragbase + s * 8) = v;
    }
}

// ---------- Kernel 2: wave-autonomous fused attention + adj@W2 row sums ----------
// 512 blocks x 256 threads (4 waves). Block owns 16 rows; wave w owns j in [w*2048,(w+1)*2048).
// No barriers in the K-loop. R8 delta vs R7: ONE added __syncthreads() before the
// epilogue reuses tile[] as the float reduction buffer. (R5-R7 had a race: waves 1-3
// clobbered wave 0's private wg tile while wave 0 could still be MFMAing chunk 7;
// float bits read as bf16 occasionally decode as NaN -> NaN h_prime. R5 passed by
// timing luck; the B-dbuf shifted wave timing and exposed it.)
__global__ __launch_bounds__(256, 2) void gat_main(
    const int* __restrict__ adj, const float* __restrict__ x,
    const float* __restrict__ W2, const float* __restrict__ f1g,
    const float* __restrict__ f2g, const unsigned short* __restrict__ hB,
    float* __restrict__ hp, float* __restrict__ ws_acc)
{
    __shared__ unsigned short tile[4][16][264];   // 33 KB, per-wave private wg tiles
    __shared__ float den_s[4][16], rs_s[4][16];

    int tid = threadIdx.x;
    int w = tid >> 6, l = tid & 63;
    int i0 = blockIdx.x * 16;

    float f1r[16];
    #pragma unroll
    for (int r = 0; r < 16; ++r) f1r[r] = f1g[i0 + r];

    float den[16], rs[16];
    #pragma unroll
    for (int r = 0; r < 16; ++r) { den[r] = 0.f; rs[r] = 0.f; }
    f32x4 acc[8] = {};

    const int jbase0 = w * 2048;
    const int* arow = adj + (size_t)i0 * 8192 + jbase0 + l * 4;
    const float* f2p = f2g + jbase0 + l * 4;
    const float* w2p = W2 + jbase0 + l * 4;

    i32x4 adjreg[16];
    f32x4 f2v, w2v;
    auto issue = [&](int c) {
        int jo = c * 256;
        f2v = *(const f32x4*)(f2p + jo);
        w2v = *(const f32x4*)(w2p + jo);
        #pragma unroll
        for (int r = 0; r < 16; ++r)
            adjreg[r] = __builtin_nontemporal_load(
                (const i32x4*)(arow + (size_t)r * 8192 + jo));
    };
    issue(0);

    const unsigned short* hBw = hB + (size_t)w * 262144 + l * 8;  // wave's ks-quarter
    const unsigned short* ap  = &tile[w][l & 15][(l >> 4) * 8];   // A-frag base

    for (int c = 0; c < 8; ++c) {
        // ---- consume chunk c: wg -> private LDS tile, den/rs lane-local ----
        #pragma unroll
        for (int r = 0; r < 16; ++r) {
            i32x4 ad = adjreg[r];
            float g[4];
            float dsum = 0.f, rsum = 0.f;
            #pragma unroll
            for (int e = 0; e < 4; ++e) {
                float tt = f1r[r] + f2v[e];
                float lr = fmaxf(tt, ALPHA * tt);     // leakyrelu
                float ex = __expf(lr);
                float gg = (ad[e] != 0) ? ex : 0.0f;
                g[e] = gg;
                dsum += gg;
                rsum += (ad[e] != 0) ? w2v[e] : 0.0f;
            }
            den[r] += dsum;
            rs[r] += rsum;
            unsigned int p0 = bf16bits(g[0]) | ((unsigned int)bf16bits(g[1]) << 16);
            unsigned int p1 = bf16bits(g[2]) | ((unsigned int)bf16bits(g[3]) << 16);
            *(uint2*)&tile[w][r][l * 4] = make_uint2(p0, p1);
        }
        // ---- prefetch chunk c+1 adj/scalars (in flight through MFMA phase) ----
        if (c < 7) issue(c + 1);

        // ---- MFMA chunk c: A from private LDS, B double-buffered from L2-resident hB ----
        const unsigned short* bp = hBw + (size_t)c * 32768;
        bf16x8 bbuf[2][8];
        #pragma unroll
        for (int ft = 0; ft < 8; ++ft)
            bbuf[0][ft] = *(const bf16x8*)(bp + ft * 512);
        #pragma unroll
        for (int ksl = 0; ksl < 8; ++ksl) {
            int cur = ksl & 1;
            if (ksl < 7) {
                const unsigned short* bk = bp + (size_t)(ksl + 1) * 4096;
                #pragma unroll
                for (int ft = 0; ft < 8; ++ft)
                    bbuf[cur ^ 1][ft] = *(const bf16x8*)(bk + ft * 512);
            }
            bf16x8 af = *(const bf16x8*)(ap + ksl * 32);
            #pragma unroll
            for (int ft = 0; ft < 8; ++ft)
                acc[ft] = __builtin_amdgcn_mfma_f32_16x16x32_bf16(af, bbuf[cur][ft], acc[ft], 0, 0, 0);
        }
    }

    // ---- lane reduction of den/rs, stash per-wave sums ----
    #pragma unroll
    for (int r = 0; r < 16; ++r) {
        float d = den[r], rr = rs[r];
        #pragma unroll
        for (int off = 1; off < 64; off <<= 1) {
            d += __shfl_xor(d, off);
            rr += __shfl_xor(rr, off);
        }
        if (l == 0) { den_s[w][r] = d; rs_s[w][r] = rr; }
    }

    // ---- barrier BEFORE reusing tile as float buffer (fixes R5-R7 race) ----
    __syncthreads();

    // ---- 4-way j-split acc reduction (reuse tile as float buffer) ----
    float* av = (float*)acc;
    if (w != 0) {
        float* dst = (float*)&tile[0][0][0] + (size_t)(w - 1) * 2048;
        #pragma unroll
        for (int j = 0; j < 32; ++j) dst[j * 64 + l] = av[j];
    }
    __syncthreads();

    if (w == 0) {
        #pragma unroll
        for (int ww = 0; ww < 3; ++ww) {
            const float* srcp = (const float*)&tile[0][0][0] + (size_t)ww * 2048;
            #pragma unroll
            for (int j = 0; j < 32; ++j) av[j] += srcp[j * 64 + l];
        }
        int q = l >> 4, col = l & 15;
        float inv[4];
        #pragma unroll
        for (int reg = 0; reg < 4; ++reg) {
            int row = q * 4 + reg;
            float dsum = den_s[0][row] + den_s[1][row] + den_s[2][row] + den_s[3][row];
            inv[reg] = (dsum != 0.f) ? 1.0f / dsum : 0.f;
        }
        #pragma unroll
        for (int ft = 0; ft < 8; ++ft) {
            #pragma unroll
            for (int reg = 0; reg < 4; ++reg) {
                int row = q * 4 + reg;
                __builtin_nontemporal_store(acc[ft][reg] * inv[reg],
                    hp + (size_t)(i0 + row) * 128 + ft * 16 + col);
            }
        }
    } else if (w == 1) {
        // out-path partial: sum_i rs[i] * x[i][:] over this block's 16 rows
        float px = 0.f, py = 0.f;
        #pragma unroll
        for (int r = 0; r < 16; ++r) {
            float rm = rs_s[0][r] + rs_s[1][r] + rs_s[2][r] + rs_s[3][r];
            const float* xr = x + (size_t)(i0 + r) * 128;
            px += rm * xr[l];
            py += rm * xr[l + 64];
        }
        atomicAdd(ws_acc + l, px);
        atomicAdd(ws_acc + l + 64, py);
    }
}

// ---------- Kernel 3: elu epilogue ----------
__global__ __launch_bounds__(128) void gat_finish(const float* __restrict__ ws_acc,
                                                  float* __restrict__ out)
{
    int t = threadIdx.x;
    float v = ws_acc[t];
    out[t] = (v > 0.f) ? v : (__expf(v) - 1.0f);
}

extern "C" void kernel_launch(void* const* d_in, const int* in_sizes, int n_in,
                              void* d_out, int out_size, void* d_ws, size_t ws_size,
                              hipStream_t stream) {
    const float* x   = (const float*)d_in[0];
    const int*   adj = (const int*)d_in[1];
    const float* W   = (const float*)d_in[2];
    const float* a   = (const float*)d_in[3];
    const float* W2  = (const float*)d_in[4];
    float* out = (float*)d_out;              // [0:128] elu out, [128:] h_prime [8192][128]

    float* wsf    = (float*)d_ws;
    float* ws_acc = wsf;                     // 128 floats
    float* f1     = wsf + 128;               // 8192 floats
    float* f2     = wsf + 128 + 8192;        // 8192 floats
    unsigned short* hB = (unsigned short*)(wsf + 128 + 2 * 8192);  // bf16, 2 MB fragment-packed

    gat_prep<<<256, 256, 0, stream>>>(x, W, a, f1, f2, hB, ws_acc);
    gat_main<<<512, 256, 0, stream>>>(adj, x, W2, f1, f2, hB, out + 128, ws_acc);
    gat_finish<<<1, 128, 0, stream>>>(ws_acc, out);
}